// Round 17
// baseline (2184.428 us; speedup 1.0000x reference)
//
#include <hip/hip_runtime.h>

#define TSTEPS 2048
#define NBATCH 512
#define H1 64
#define H2 16

typedef _Float16 h2v __attribute__((ext_vector_type(2)));

__device__ __forceinline__ float fsig(float x) {
    return __builtin_amdgcn_rcpf(1.0f + __builtin_amdgcn_exp2f(-1.4426950408889634f * x));
}
__device__ __forceinline__ float ftanh(float x) {
    // tanh(x) = 1 - 2/(exp2(2x*log2e)+1); saturates correctly at +-inf
    return 1.0f - 2.0f * __builtin_amdgcn_rcpf(1.0f + __builtin_amdgcn_exp2f(2.8853900817779268f * x));
}
__device__ __forceinline__ float act(float x, float k2) {
    return k2 * fsig(k2 * x) - (k2 - 1.0f);
}

#if __has_builtin(__builtin_amdgcn_fdot2)
__device__ __forceinline__ float dot2(int wp, int hp, float acc) {
    return __builtin_amdgcn_fdot2(__builtin_bit_cast(h2v, wp),
                                  __builtin_bit_cast(h2v, hp), acc, false);
}
#else
__device__ __forceinline__ float dot2(int wp, int hp, float acc) {
    h2v a = __builtin_bit_cast(h2v, wp), b = __builtin_bit_cast(h2v, hp);
    return acc + (float)a.x * (float)b.x + (float)a.y * (float)b.y;
}
#endif

__device__ __forceinline__ int packh2(float a, float b) {
    h2v v; v.x = (_Float16)a; v.y = (_Float16)b;
    return __builtin_bit_cast(int, v);
}
template<int CTRL>
__device__ __forceinline__ float dpp_bcast(float v) {   // quad broadcast
    int r = __builtin_amdgcn_mov_dpp(__float_as_int(v), CTRL, 0xF, 0xF, true);
    return __int_as_float(r);
}

// TWO BATCHES PER WAVE, one wave per block, zero barriers.
// r14=r15=1400cyc/step @ VALUBusy 34% proved the binder is EXPOSED LATENCY
// (each wave alone on its SIMD; issue ~480 cyc, stalls ~900). r16's SGPR
// broadcast made it worse (serial readlanes). Fix: double the independent
// work INSIDE the wave. Weights are batch-invariant -- 2 batches share every
// weight register and every streamed LDS weight read; only state (acc, c1/c2,
// h-chunks, ~45 regs) duplicates. 16 independent dot chains now interleave,
// so one batch's dep-stalls are filled by the other's issue.
// Register budget: only w1 gate-i resident (32); f,g,o,w2,wh2 stream from LDS
// (34 b128/step ~ 410 DS-pipe cyc, hidden under ~830 cyc VALU issue).
// 256 blocks = 1 block/CU.
__global__ void __launch_bounds__(64, 1)
__attribute__((amdgpu_waves_per_eu(1, 1)))
lstm2_fused(const float* __restrict__ x,      // [512, 2048, 1]
            const float* __restrict__ w_ih1,  // [256, 1]
            const float* __restrict__ w_hh1,  // [256, 64]
            const float* __restrict__ b_ih1,  // [256]
            const float* __restrict__ b_hh1,  // [256]
            const float* __restrict__ w_ih2,  // [64, 64]
            const float* __restrict__ w_hh2,  // [64, 16]
            const float* __restrict__ b_ih2,  // [64]
            const float* __restrict__ b_hh2,  // [64]
            float* __restrict__ out)          // [512, 2048, 16]
{
    const int lane = threadIdx.x;     // 64 threads = 1 wave
    const int b0   = blockIdx.x * 2;  // batches b0, b0+1

    __shared__ int4     wlds[34][64];      // 34.8 KB streamed weights
    __shared__ float    x_lds[2][TSTEPS];  // 16 KB
    __shared__ _Float16 h1_lds[2][H1];     // per-batch h1
    __shared__ _Float16 h2_lds[2][H2];     // per-batch h2
    __shared__ float    ring[32][2][H2];   // 4 KB output ring

    // ---- stage x for both batches ----
    #pragma unroll
    for (int bb = 0; bb < 2; ++bb) {
        const float4* xs = (const float4*)(x + (size_t)(b0 + bb) * TSTEPS);
        float4* xd = (float4*)x_lds[bb];
        #pragma unroll
        for (int i = 0; i < 8; ++i) xd[lane + 64 * i] = xs[lane + 64 * i];
    }
    h1_lds[0][lane] = (_Float16)0.0f;
    h1_lds[1][lane] = (_Float16)0.0f;
    if (lane < 16) { h2_lds[0][lane] = (_Float16)0.0f; h2_lds[1][lane] = (_Float16)0.0f; }

    // ---- register-resident: w1 gate i only (row = lane) ----
    int w1i[32];
    {
        const float* wri = w_hh1 + (size_t)lane * H1;
        #pragma unroll
        for (int k = 0; k < 32; ++k) w1i[k] = packh2(wri[2 * k], wri[2 * k + 1]);
    }
    // ---- LDS-streamed: f rows 0-7, g rows 8-15, o rows 16-23, w2 rows 24-31,
    //      wh2 rows 32-33. Row r holds packed pairs 4r..4r+3 (lane column). ----
    const int m  = lane >> 2;
    const int g2 = lane & 3;
    const int r2 = g2 * H2 + m;
    {
        const float* wrf = w_hh1 + (size_t)(H1 + lane) * H1;
        const float* wrg = w_hh1 + (size_t)(2 * H1 + lane) * H1;
        const float* wro = w_hh1 + (size_t)(3 * H1 + lane) * H1;
        const float* wr2 = w_ih2 + (size_t)r2 * H1;
        #pragma unroll
        for (int r = 0; r < 8; ++r) {
            wlds[r][lane] = make_int4(
                packh2(wrf[8*r+0], wrf[8*r+1]), packh2(wrf[8*r+2], wrf[8*r+3]),
                packh2(wrf[8*r+4], wrf[8*r+5]), packh2(wrf[8*r+6], wrf[8*r+7]));
            wlds[8 + r][lane] = make_int4(
                packh2(wrg[8*r+0], wrg[8*r+1]), packh2(wrg[8*r+2], wrg[8*r+3]),
                packh2(wrg[8*r+4], wrg[8*r+5]), packh2(wrg[8*r+6], wrg[8*r+7]));
            wlds[16 + r][lane] = make_int4(
                packh2(wro[8*r+0], wro[8*r+1]), packh2(wro[8*r+2], wro[8*r+3]),
                packh2(wro[8*r+4], wro[8*r+5]), packh2(wro[8*r+6], wro[8*r+7]));
            wlds[24 + r][lane] = make_int4(
                packh2(wr2[8*r+0], wr2[8*r+1]), packh2(wr2[8*r+2], wr2[8*r+3]),
                packh2(wr2[8*r+4], wr2[8*r+5]), packh2(wr2[8*r+6], wr2[8*r+7]));
        }
        const float* wrh = w_hh2 + (size_t)r2 * H2;
        wlds[32][lane] = make_int4(packh2(wrh[0], wrh[1]),  packh2(wrh[2], wrh[3]),
                                   packh2(wrh[4], wrh[5]),  packh2(wrh[6], wrh[7]));
        wlds[33][lane] = make_int4(packh2(wrh[8], wrh[9]),  packh2(wrh[10], wrh[11]),
                                   packh2(wrh[12], wrh[13]), packh2(wrh[14], wrh[15]));
    }

    // ---- per-gate scalars (batch-invariant) ----
    const float wxi = w_ih1[lane],        wxf = w_ih1[H1 + lane];
    const float wxg = w_ih1[2*H1 + lane], wxo = w_ih1[3*H1 + lane];
    const float bsi = b_ih1[lane] + b_hh1[lane];
    const float bsf = b_ih1[H1+lane] + b_hh1[H1+lane];
    const float bsg = b_ih1[2*H1+lane] + b_hh1[2*H1+lane];
    const float bso = b_ih1[3*H1+lane] + b_hh1[3*H1+lane];
    const float bs2 = b_ih2[r2] + b_hh2[r2];
    const float k22 = (g2 == 2) ? 2.0f : 1.0f;

    float c1_0 = 0.f, c1_1 = 0.f;     // L1 cells
    float c2_0 = 0.f, c2_1 = 0.f;     // L2 cells (replicated per quad)
    float* outb0 = out + (size_t)b0 * TSTEPS * H2;
    float* outb1 = out + (size_t)(b0 + 1) * TSTEPS * H2;

    const int4* wl = &wlds[0][0];     // index row*64 + lane

// per-chunk dots for one batch: i from regs, f/g/o/w2 from streamed chunk regs
#define DOTS1(C, hA, hB, ai, af, ag, ao, q0, q1, q2, q3) do {                  \
    ai = dot2(w1i[8*C+0], hA.x, ai); ai = dot2(w1i[8*C+1], hA.y, ai);          \
    ai = dot2(w1i[8*C+2], hA.z, ai); ai = dot2(w1i[8*C+3], hA.w, ai);          \
    ai = dot2(w1i[8*C+4], hB.x, ai); ai = dot2(w1i[8*C+5], hB.y, ai);          \
    ai = dot2(w1i[8*C+6], hB.z, ai); ai = dot2(w1i[8*C+7], hB.w, ai);          \
    af = dot2(cf.x,  hA.x, af); af = dot2(cf.y,  hA.y, af);                    \
    af = dot2(cf.z,  hA.z, af); af = dot2(cf.w,  hA.w, af);                    \
    af = dot2(cf2.x, hB.x, af); af = dot2(cf2.y, hB.y, af);                    \
    af = dot2(cf2.z, hB.z, af); af = dot2(cf2.w, hB.w, af);                    \
    ag = dot2(cg.x,  hA.x, ag); ag = dot2(cg.y,  hA.y, ag);                    \
    ag = dot2(cg.z,  hA.z, ag); ag = dot2(cg.w,  hA.w, ag);                    \
    ag = dot2(cg2.x, hB.x, ag); ag = dot2(cg2.y, hB.y, ag);                    \
    ag = dot2(cg2.z, hB.z, ag); ag = dot2(cg2.w, hB.w, ag);                    \
    ao = dot2(co.x,  hA.x, ao); ao = dot2(co.y,  hA.y, ao);                    \
    ao = dot2(co.z,  hA.z, ao); ao = dot2(co.w,  hA.w, ao);                    \
    ao = dot2(co2.x, hB.x, ao); ao = dot2(co2.y, hB.y, ao);                    \
    ao = dot2(co2.z, hB.z, ao); ao = dot2(co2.w, hB.w, ao);                    \
    q0 = dot2(cu.x,  hA.x, q0); q1 = dot2(cu.y,  hA.y, q1);                    \
    q2 = dot2(cu.z,  hA.z, q2); q3 = dot2(cu.w,  hA.w, q3);                    \
    q0 = dot2(cu2.x, hB.x, q0); q1 = dot2(cu2.y, hB.y, q1);                    \
    q2 = dot2(cu2.z, hB.z, q2); q3 = dot2(cu2.w, hB.w, q3);                    \
} while (0)

    for (int p = 0; p <= TSTEPS; ++p) {
        // ---- output flush: every 16 steps, both batches (same-wave FIFO) ----
        const int tau_f = p - 1;
        if (tau_f >= 31 && (tau_f & 15) == 15) {
            const int tau0 = (tau_f & ~15) - 16;
            const int tt = tau0 + (lane >> 2), ch0 = (lane & 3) * 4;
            float4 v0 = *(const float4*)&ring[tt & 31][0][ch0];
            float4 v1 = *(const float4*)&ring[tt & 31][1][ch0];
            *(float4*)(outb0 + (size_t)tt * H2 + ch0) = v0;
            *(float4*)(outb1 + (size_t)tt * H2 + ch0) = v1;
        }

        const int pm = p & (TSTEPS - 1);
        const float xv0 = x_lds[0][pm], xv1 = x_lds[1][pm];
        float ai0 = bsi + wxi * xv0, af0 = bsf + wxf * xv0;
        float ag0 = bsg + wxg * xv0, ao0 = bso + wxo * xv0;
        float ai1 = bsi + wxi * xv1, af1 = bsf + wxf * xv1;
        float ag1 = bsg + wxg * xv1, ao1 = bso + wxo * xv1;
        float q00 = bs2, q10 = 0.f, q20 = 0.f, q30 = 0.f;
        float q01 = bs2, q11 = 0.f, q21 = 0.f, q31 = 0.f;
        int4 vh0, vh1;

        const int4* hs0 = (const int4*)h1_lds[0];
        const int4* hs1 = (const int4*)h1_lds[1];

        #pragma unroll
        for (int c = 0; c < 4; ++c) {
            int4 cf  = wl[(2*c)      * 64 + lane];
            int4 cf2 = wl[(2*c + 1)  * 64 + lane];
            int4 cg  = wl[(8 + 2*c)  * 64 + lane];
            int4 cg2 = wl[(9 + 2*c)  * 64 + lane];
            int4 co  = wl[(16 + 2*c) * 64 + lane];
            int4 co2 = wl[(17 + 2*c) * 64 + lane];
            int4 cu  = wl[(24 + 2*c) * 64 + lane];
            int4 cu2 = wl[(25 + 2*c) * 64 + lane];
            if (c == 2) { vh0 = wl[32 * 64 + lane]; vh1 = wl[33 * 64 + lane]; }
            int4 hA0 = hs0[2*c], hB0 = hs0[2*c + 1];
            int4 hA1 = hs1[2*c], hB1 = hs1[2*c + 1];
            DOTS1(c, hA0, hB0, ai0, af0, ag0, ao0, q00, q10, q20, q30);
            DOTS1(c, hA1, hB1, ai1, af1, ag1, ao1, q01, q11, q21, q31);
        }

        // ===== Layer 1 finish, timestep p (both batches) =====
        if (p < TSTEPS) {
            float gi0 = fsig(ai0), gf0 = fsig(af0), gg0 = ftanh(ag0), go0 = fsig(ao0);
            float gi1 = fsig(ai1), gf1 = fsig(af1), gg1 = ftanh(ag1), go1 = fsig(ao1);
            c1_0 = gf0 * c1_0 + gi0 * gg0;
            c1_1 = gf1 * c1_1 + gi1 * gg1;
            float h1n0 = go0 * ftanh(c1_0);
            float h1n1 = go1 * ftanh(c1_1);
            h1_lds[0][lane] = (_Float16)h1n0;   // same-wave FIFO
            h1_lds[1][lane] = (_Float16)h1n1;
        }

        // ===== Layer 2 finish, timestep p-1 (both batches) =====
        if (p >= 1) {
            const int4* h2p0 = (const int4*)h2_lds[0];
            const int4* h2p1 = (const int4*)h2_lds[1];
            int4 u00 = h2p0[0], u01 = h2p0[1];
            int4 u10 = h2p1[0], u11 = h2p1[1];
            q00 = dot2(vh0.x, u00.x, q00); q10 = dot2(vh0.y, u00.y, q10);
            q20 = dot2(vh0.z, u00.z, q20); q30 = dot2(vh0.w, u00.w, q30);
            q00 = dot2(vh1.x, u01.x, q00); q10 = dot2(vh1.y, u01.y, q10);
            q20 = dot2(vh1.z, u01.z, q20); q30 = dot2(vh1.w, u01.w, q30);
            q01 = dot2(vh0.x, u10.x, q01); q11 = dot2(vh0.y, u10.y, q11);
            q21 = dot2(vh0.z, u10.z, q21); q31 = dot2(vh0.w, u10.w, q31);
            q01 = dot2(vh1.x, u11.x, q01); q11 = dot2(vh1.y, u11.y, q11);
            q21 = dot2(vh1.z, u11.z, q21); q31 = dot2(vh1.w, u11.w, q31);

            float av0 = act((q00 + q10) + (q20 + q30), k22);
            float av1 = act((q01 + q11) + (q21 + q31), k22);
            float gi0 = dpp_bcast<0x00>(av0), gf0 = dpp_bcast<0x55>(av0);
            float gg0 = dpp_bcast<0xAA>(av0), go0 = dpp_bcast<0xFF>(av0);
            float gi1 = dpp_bcast<0x00>(av1), gf1 = dpp_bcast<0x55>(av1);
            float gg1 = dpp_bcast<0xAA>(av1), go1 = dpp_bcast<0xFF>(av1);
            c2_0 = gf0 * c2_0 + gi0 * gg0;
            c2_1 = gf1 * c2_1 + gi1 * gg1;
            float h2n0 = go0 * ftanh(c2_0);
            float h2n1 = go1 * ftanh(c2_1);
            if (g2 == 0) {
                h2_lds[0][m] = (_Float16)h2n0;
                h2_lds[1][m] = (_Float16)h2n1;
                ring[(p - 1) & 31][0][m] = h2n0;
                ring[(p - 1) & 31][1][m] = h2n1;
            }
        }
    }
#undef DOTS1

    // ---- tail flush: timesteps 2032..2047 (same wave -> FIFO safe) ----
    {
        const int tt = 2032 + (lane >> 2), ch0 = (lane & 3) * 4;
        float4 v0 = *(const float4*)&ring[tt & 31][0][ch0];
        float4 v1 = *(const float4*)&ring[tt & 31][1][ch0];
        *(float4*)(outb0 + (size_t)tt * H2 + ch0) = v0;
        *(float4*)(outb1 + (size_t)tt * H2 + ch0) = v1;
    }
}

extern "C" void kernel_launch(void* const* d_in, const int* in_sizes, int n_in,
                              void* d_out, int out_size, void* d_ws, size_t ws_size,
                              hipStream_t stream) {
    const float* x     = (const float*)d_in[0];
    const float* w_ih1 = (const float*)d_in[1];
    const float* w_hh1 = (const float*)d_in[2];
    const float* b_ih1 = (const float*)d_in[3];
    const float* b_hh1 = (const float*)d_in[4];
    const float* w_ih2 = (const float*)d_in[5];
    const float* w_hh2 = (const float*)d_in[6];
    const float* b_ih2 = (const float*)d_in[7];
    const float* b_hh2 = (const float*)d_in[8];
    float* out = (float*)d_out;

    lstm2_fused<<<NBATCH / 2, 64, 0, stream>>>(x, w_ih1, w_hh1, b_ih1, b_hh1,
                                               w_ih2, w_hh2, b_ih2, b_hh2, out);
}

// Round 18
// 1306.100 us; speedup vs baseline: 1.6725x; 1.6725x over previous
//
#include <hip/hip_runtime.h>

#define TSTEPS 2048
#define NBATCH 512
#define H1 64
#define H2 16

typedef _Float16 h2v __attribute__((ext_vector_type(2)));

__device__ __forceinline__ float fsig(float x) {
    return __builtin_amdgcn_rcpf(1.0f + __builtin_amdgcn_exp2f(-1.4426950408889634f * x));
}
__device__ __forceinline__ float ftanh(float x) {
    // tanh(x) = 1 - 2/(exp2(2x*log2e)+1); saturates correctly at +-inf
    return 1.0f - 2.0f * __builtin_amdgcn_rcpf(1.0f + __builtin_amdgcn_exp2f(2.8853900817779268f * x));
}
// branchless: k2==1 -> sigmoid(x); k2==2 -> tanh(x) = 2*sig(2x)-1
__device__ __forceinline__ float act(float x, float k2) {
    return k2 * fsig(k2 * x) - (k2 - 1.0f);
}

#if __has_builtin(__builtin_amdgcn_fdot2)
__device__ __forceinline__ float dot2(int wp, int hp, float acc) {
    return __builtin_amdgcn_fdot2(__builtin_bit_cast(h2v, wp),
                                  __builtin_bit_cast(h2v, hp), acc, false);
}
#else
__device__ __forceinline__ float dot2(int wp, int hp, float acc) {
    h2v a = __builtin_bit_cast(h2v, wp), b = __builtin_bit_cast(h2v, hp);
    return acc + (float)a.x * (float)b.x + (float)a.y * (float)b.y;
}
#endif

__device__ __forceinline__ int packh2(float a, float b) {
    h2v v; v.x = (_Float16)a; v.y = (_Float16)b;
    return __builtin_bit_cast(int, v);
}
template<int CTRL>
__device__ __forceinline__ float dpp_bcast(float v) {   // quad broadcast
    int r = __builtin_amdgcn_mov_dpp(__float_as_int(v), CTRL, 0xF, 0xF, true);
    return __int_as_float(r);
}

// PRODUCER-CONSUMER WAVE SPECIALIZATION, zero in-loop barriers.
// r17 verdict: merging work into one wave SUMS latencies (in-order wave);
// overlap on CDNA comes from separate waves on separate SIMDs. L1->L2 is
// one-directional (h2 never feeds L1), so L2 leaves L1's serial loop:
//   wave 0: L1 only -- 128 dot2/step, h1 -> 64-deep LDS ring + volatile
//           progress flag (DS ops in-order per wave: data before flag).
//   wave 1: spins on flag (s_sleep-throttled), consumes h1 ring, computes
//           L2 (40 dot2/step, far faster), stores h2 straight to global
//           (64 B contiguous; store latency never touches wave 0).
// Backpressure: wave0 polls wave1's consumption counter every 32 steps
// (31-step slack; wave1 is faster so this never spins in practice).
// 512 blocks x 128 thr = 4 waves/CU = 1 per SIMD.
__global__ void __launch_bounds__(128, 1)
__attribute__((amdgpu_waves_per_eu(1, 1)))
lstm2_fused(const float* __restrict__ x,      // [512, 2048, 1]
            const float* __restrict__ w_ih1,  // [256, 1]
            const float* __restrict__ w_hh1,  // [256, 64]
            const float* __restrict__ b_ih1,  // [256]
            const float* __restrict__ b_hh1,  // [256]
            const float* __restrict__ w_ih2,  // [64, 64]
            const float* __restrict__ w_hh2,  // [64, 16]
            const float* __restrict__ b_ih2,  // [64]
            const float* __restrict__ b_hh2,  // [64]
            float* __restrict__ out)          // [512, 2048, 16]
{
    const int tid  = threadIdx.x;
    const int lane = tid & 63;
    const int b    = blockIdx.x;

    __shared__ int4     wgo[16][64];        // 16 KB: w1 gate g rows 0-7, gate o rows 8-15
    __shared__ float    x_lds[TSTEPS];      // 8 KB
    __shared__ _Float16 h1ring[64][H1];     // 8 KB, slot t&63 = h1(t)
    __shared__ _Float16 h2buf[H2];          // wave1-private recurrence buffer
    __shared__ int      prog_s;             // steps completed by wave0
    __shared__ int      cons_s;             // steps completed by wave1

    volatile int* vprog = &prog_s;
    volatile int* vcons = &cons_s;

    // ---------------- init (before the single barrier) ----------------
    int   w1i[32], w1f[32];
    float wxi = 0, wxf = 0, wxg = 0, wxo = 0, bsi = 0, bsf = 0, bsg = 0, bso = 0;
    int   w2r[32], wh2r[8];
    float bs2 = 0, k22 = 1.f;

    if (tid < 64) {
        // stage x[b,:]
        const float4* xs = (const float4*)(x + (size_t)b * TSTEPS);
        float4* xd = (float4*)x_lds;
        #pragma unroll
        for (int i = 0; i < 8; ++i) xd[lane + 64 * i] = xs[lane + 64 * i];
        // register weights: gates i, f (row lane / 64+lane)
        const float* wri = w_hh1 + (size_t)lane * H1;
        const float* wrf = w_hh1 + (size_t)(H1 + lane) * H1;
        #pragma unroll
        for (int k = 0; k < 32; ++k) {
            w1i[k] = packh2(wri[2 * k], wri[2 * k + 1]);
            w1f[k] = packh2(wrf[2 * k], wrf[2 * k + 1]);
        }
        // LDS-streamed weights: gates g, o (lane-private columns)
        const float* wrg = w_hh1 + (size_t)(2 * H1 + lane) * H1;
        const float* wro = w_hh1 + (size_t)(3 * H1 + lane) * H1;
        #pragma unroll
        for (int r = 0; r < 8; ++r) {
            wgo[r][lane] = make_int4(
                packh2(wrg[8*r+0], wrg[8*r+1]), packh2(wrg[8*r+2], wrg[8*r+3]),
                packh2(wrg[8*r+4], wrg[8*r+5]), packh2(wrg[8*r+6], wrg[8*r+7]));
            wgo[8 + r][lane] = make_int4(
                packh2(wro[8*r+0], wro[8*r+1]), packh2(wro[8*r+2], wro[8*r+3]),
                packh2(wro[8*r+4], wro[8*r+5]), packh2(wro[8*r+6], wro[8*r+7]));
        }
        wxi = w_ih1[lane];          wxf = w_ih1[H1 + lane];
        wxg = w_ih1[2*H1 + lane];   wxo = w_ih1[3*H1 + lane];
        bsi = b_ih1[lane]        + b_hh1[lane];
        bsf = b_ih1[H1 + lane]   + b_hh1[H1 + lane];
        bsg = b_ih1[2*H1 + lane] + b_hh1[2*H1 + lane];
        bso = b_ih1[3*H1 + lane] + b_hh1[3*H1 + lane];
        if (lane == 0) *vprog = 0;
    } else {
        const int m = lane >> 2, g2 = lane & 3;
        const int r2 = g2 * H2 + m;
        #pragma unroll
        for (int k = 0; k < 32; ++k)
            w2r[k] = packh2(w_ih2[(size_t)r2 * H1 + 2*k], w_ih2[(size_t)r2 * H1 + 2*k + 1]);
        #pragma unroll
        for (int k = 0; k < 8; ++k)
            wh2r[k] = packh2(w_hh2[(size_t)r2 * H2 + 2*k], w_hh2[(size_t)r2 * H2 + 2*k + 1]);
        bs2 = b_ih2[r2] + b_hh2[r2];
        k22 = (g2 == 2) ? 2.0f : 1.0f;
        if (lane < 16) h2buf[lane] = (_Float16)0.0f;
        if (lane == 0) *vcons = 0;
    }
    __syncthreads();   // the ONLY barrier

    if (tid < 64) {
        // =================== WAVE 0: L1 producer ===================
        float c1 = 0.0f;
        int4 hp[8];                        // h1(t-1) pairs; h1(-1)=0
        #pragma unroll
        for (int i = 0; i < 8; ++i) hp[i] = make_int4(0, 0, 0, 0);

        for (int t = 0; t < TSTEPS; ++t) {
            if (t >= 64 && (t & 31) == 0) {            // ring backpressure
                while (*vcons < t - 32) __builtin_amdgcn_s_sleep(8);
            }
            const float xv = x_lds[t];
            float ai = bsi + wxi * xv, af = bsf + wxf * xv;
            float ag = bsg + wxg * xv, ao = bso + wxo * xv;
            #pragma unroll
            for (int c = 0; c < 4; ++c) {
                int4 cg  = wgo[2*c][lane],     cg2 = wgo[2*c + 1][lane];
                int4 co  = wgo[8 + 2*c][lane], co2 = wgo[9 + 2*c][lane];
                int4 hA = hp[2*c], hB = hp[2*c + 1];
                ai = dot2(w1i[8*c+0], hA.x, ai); ai = dot2(w1i[8*c+1], hA.y, ai);
                ai = dot2(w1i[8*c+2], hA.z, ai); ai = dot2(w1i[8*c+3], hA.w, ai);
                ai = dot2(w1i[8*c+4], hB.x, ai); ai = dot2(w1i[8*c+5], hB.y, ai);
                ai = dot2(w1i[8*c+6], hB.z, ai); ai = dot2(w1i[8*c+7], hB.w, ai);
                af = dot2(w1f[8*c+0], hA.x, af); af = dot2(w1f[8*c+1], hA.y, af);
                af = dot2(w1f[8*c+2], hA.z, af); af = dot2(w1f[8*c+3], hA.w, af);
                af = dot2(w1f[8*c+4], hB.x, af); af = dot2(w1f[8*c+5], hB.y, af);
                af = dot2(w1f[8*c+6], hB.z, af); af = dot2(w1f[8*c+7], hB.w, af);
                ag = dot2(cg.x,  hA.x, ag); ag = dot2(cg.y,  hA.y, ag);
                ag = dot2(cg.z,  hA.z, ag); ag = dot2(cg.w,  hA.w, ag);
                ag = dot2(cg2.x, hB.x, ag); ag = dot2(cg2.y, hB.y, ag);
                ag = dot2(cg2.z, hB.z, ag); ag = dot2(cg2.w, hB.w, ag);
                ao = dot2(co.x,  hA.x, ao); ao = dot2(co.y,  hA.y, ao);
                ao = dot2(co.z,  hA.z, ao); ao = dot2(co.w,  hA.w, ao);
                ao = dot2(co2.x, hB.x, ao); ao = dot2(co2.y, hB.y, ao);
                ao = dot2(co2.z, hB.z, ao); ao = dot2(co2.w, hB.w, ao);
            }
            float gi = fsig(ai), gf = fsig(af), gg = ftanh(ag), go = fsig(ao);
            c1 = gf * c1 + gi * gg;
            float h1n = go * ftanh(c1);
            h1ring[t & 63][lane] = (_Float16)h1n;      // data ...
            asm volatile("" ::: "memory");
            if (lane == 0) *vprog = t + 1;             // ... then flag (DS in-order)
            asm volatile("" ::: "memory");
            const int4* hs = (const int4*)h1ring[t & 63];   // prefetch own next-step h
            #pragma unroll
            for (int i = 0; i < 8; ++i) hp[i] = hs[i];      // same-wave FIFO
        }
    } else {
        // =================== WAVE 1: L2 consumer ===================
        const int m = lane >> 2, g2 = lane & 3;
        float c2 = 0.0f;
        int seen = 0;
        float* outb = out + (size_t)b * TSTEPS * H2;

        for (int t = 0; t < TSTEPS; ++t) {
            if (seen < t + 1) {
                while ((seen = *vprog) < t + 1) __builtin_amdgcn_s_sleep(8);
            }
            asm volatile("" ::: "memory");
            const int4* hs = (const int4*)h1ring[t & 63];   // h1(t), published
            int4 hA = hs[0], hB = hs[1], hC = hs[2], hD = hs[3];
            int4 hE = hs[4], hF = hs[5], hG = hs[6], hH = hs[7];

            float q0 = bs2, q1 = 0.f, q2 = 0.f, q3 = 0.f;
            q0 = dot2(w2r[0],  hA.x, q0); q1 = dot2(w2r[1],  hA.y, q1);
            q2 = dot2(w2r[2],  hA.z, q2); q3 = dot2(w2r[3],  hA.w, q3);
            q0 = dot2(w2r[4],  hB.x, q0); q1 = dot2(w2r[5],  hB.y, q1);
            q2 = dot2(w2r[6],  hB.z, q2); q3 = dot2(w2r[7],  hB.w, q3);
            q0 = dot2(w2r[8],  hC.x, q0); q1 = dot2(w2r[9],  hC.y, q1);
            q2 = dot2(w2r[10], hC.z, q2); q3 = dot2(w2r[11], hC.w, q3);
            q0 = dot2(w2r[12], hD.x, q0); q1 = dot2(w2r[13], hD.y, q1);
            q2 = dot2(w2r[14], hD.z, q2); q3 = dot2(w2r[15], hD.w, q3);
            q0 = dot2(w2r[16], hE.x, q0); q1 = dot2(w2r[17], hE.y, q1);
            q2 = dot2(w2r[18], hE.z, q2); q3 = dot2(w2r[19], hE.w, q3);
            q0 = dot2(w2r[20], hF.x, q0); q1 = dot2(w2r[21], hF.y, q1);
            q2 = dot2(w2r[22], hF.z, q2); q3 = dot2(w2r[23], hF.w, q3);
            q0 = dot2(w2r[24], hG.x, q0); q1 = dot2(w2r[25], hG.y, q1);
            q2 = dot2(w2r[26], hG.z, q2); q3 = dot2(w2r[27], hG.w, q3);
            q0 = dot2(w2r[28], hH.x, q0); q1 = dot2(w2r[29], hH.y, q1);
            q2 = dot2(w2r[30], hH.z, q2); q3 = dot2(w2r[31], hH.w, q3);

            const int4* h2p = (const int4*)h2buf;           // h2(t-1), same-wave FIFO
            int4 u0 = h2p[0], u1 = h2p[1];
            q0 = dot2(wh2r[0], u0.x, q0); q1 = dot2(wh2r[1], u0.y, q1);
            q2 = dot2(wh2r[2], u0.z, q2); q3 = dot2(wh2r[3], u0.w, q3);
            q0 = dot2(wh2r[4], u1.x, q0); q1 = dot2(wh2r[5], u1.y, q1);
            q2 = dot2(wh2r[6], u1.z, q2); q3 = dot2(wh2r[7], u1.w, q3);

            float av = act((q0 + q1) + (q2 + q3), k22);
            float gi = dpp_bcast<0x00>(av), gf = dpp_bcast<0x55>(av);
            float gg = dpp_bcast<0xAA>(av), go = dpp_bcast<0xFF>(av);
            c2 = gf * c2 + gi * gg;
            float h2n = go * ftanh(c2);
            if (g2 == 0) {
                h2buf[m] = (_Float16)h2n;
                outb[(size_t)t * H2 + m] = h2n;    // 16 lanes -> 64 B contiguous
            }
            if ((t & 15) == 15) {
                asm volatile("" ::: "memory");
                if (lane == 0) *vcons = t + 1;     // consumption counter
            }
        }
    }
}

extern "C" void kernel_launch(void* const* d_in, const int* in_sizes, int n_in,
                              void* d_out, int out_size, void* d_ws, size_t ws_size,
                              hipStream_t stream) {
    const float* x     = (const float*)d_in[0];
    const float* w_ih1 = (const float*)d_in[1];
    const float* w_hh1 = (const float*)d_in[2];
    const float* b_ih1 = (const float*)d_in[3];
    const float* b_hh1 = (const float*)d_in[4];
    const float* w_ih2 = (const float*)d_in[5];
    const float* w_hh2 = (const float*)d_in[6];
    const float* b_ih2 = (const float*)d_in[7];
    const float* b_hh2 = (const float*)d_in[8];
    float* out = (float*)d_out;

    lstm2_fused<<<NBATCH, 128, 0, stream>>>(x, w_ih1, w_hh1, b_ih1, b_hh1,
                                            w_ih2, w_hh2, b_ih2, b_hh2, out);
}

// Round 19
// 1217.296 us; speedup vs baseline: 1.7945x; 1.0730x over previous
//
#include <hip/hip_runtime.h>

#define TSTEPS 2048
#define NBATCH 512
#define H1 64
#define H2 16

typedef _Float16 h2v __attribute__((ext_vector_type(2)));

__device__ __forceinline__ float fsig(float x) {
    return __builtin_amdgcn_rcpf(1.0f + __builtin_amdgcn_exp2f(-1.4426950408889634f * x));
}
__device__ __forceinline__ float ftanh(float x) {
    // tanh(x) = 1 - 2/(exp2(2x*log2e)+1); saturates correctly at +-inf
    return 1.0f - 2.0f * __builtin_amdgcn_rcpf(1.0f + __builtin_amdgcn_exp2f(2.8853900817779268f * x));
}
// branchless: k2==1 -> sigmoid(x); k2==2 -> tanh(x) = 2*sig(2x)-1
__device__ __forceinline__ float act(float x, float k2) {
    return k2 * fsig(k2 * x) - (k2 - 1.0f);
}

#if __has_builtin(__builtin_amdgcn_fdot2)
__device__ __forceinline__ float dot2(int wp, int hp, float acc) {
    return __builtin_amdgcn_fdot2(__builtin_bit_cast(h2v, wp),
                                  __builtin_bit_cast(h2v, hp), acc, false);
}
#else
__device__ __forceinline__ float dot2(int wp, int hp, float acc) {
    h2v a = __builtin_bit_cast(h2v, wp), b = __builtin_bit_cast(h2v, hp);
    return acc + (float)a.x * (float)b.x + (float)a.y * (float)b.y;
}
#endif

__device__ __forceinline__ int packh2(float a, float b) {
    h2v v; v.x = (_Float16)a; v.y = (_Float16)b;
    return __builtin_bit_cast(int, v);
}
template<int CTRL>
__device__ __forceinline__ float dpp_bcast(float v) {   // quad broadcast
    int r = __builtin_amdgcn_mov_dpp(__float_as_int(v), CTRL, 0xF, 0xF, true);
    return __int_as_float(r);
}

// ONE WAVE PER BATCH, ZERO BARRIERS — r15 math, re-pipelined scheduling:
// r18 verdict: all cross-wave schemes cost >=180 cyc/step; single-wave stands.
// r15 residual (1450 cyc, VALU 490): ~410 cyc DS occupancy (34 ds_read b128)
// issued just-in-time -> ~100 cyc exposed per chunk + cold h2/pair0 reads.
// VGPR audit r13/r15/r17: the allocator grants structural liveness (92/132/
// 136 exact matches) -- the "cap" was a pin artifact. So: explicit ping-pong
// chunk buffers (issue chunk c+1's 6 reads during chunk c's dots; next-step
// chunk0 during the tail), wh2 hoisted resident, h2 pre-read at step top,
// next-step h-pair0 read right after the h1 ds_write (DS FIFO). Liveness ~190.
__global__ void __launch_bounds__(64, 1)
__attribute__((amdgpu_waves_per_eu(1, 1)))
lstm2_fused(const float* __restrict__ x,      // [512, 2048, 1]
            const float* __restrict__ w_ih1,  // [256, 1]
            const float* __restrict__ w_hh1,  // [256, 64]
            const float* __restrict__ b_ih1,  // [256]
            const float* __restrict__ b_hh1,  // [256]
            const float* __restrict__ w_ih2,  // [64, 64]
            const float* __restrict__ w_hh2,  // [64, 16]
            const float* __restrict__ b_ih2,  // [64]
            const float* __restrict__ b_hh2,  // [64]
            float* __restrict__ out)          // [512, 2048, 16]
{
    const int lane = threadIdx.x;     // 64 threads = 1 wave
    const int b    = blockIdx.x;      // 1 batch per block

    __shared__ int4     wlds[26][64];      // 26.6 KB streamed weights
    __shared__ float    x_lds[TSTEPS];     // 8 KB
    __shared__ _Float16 h1_lds[H1];        // 128 B
    __shared__ _Float16 h2_lds[H2];        // 32 B
    __shared__ float    ring[32][H2];      // 2 KB output ring

    // ---- stage x[b,:] ----
    {
        const float4* xs = (const float4*)(x + (size_t)b * TSTEPS);
        float4* xd = (float4*)x_lds;
        #pragma unroll
        for (int i = 0; i < 8; ++i) xd[lane + 64 * i] = xs[lane + 64 * i];
    }
    if (lane < 32) ((int*)h1_lds)[lane] = 0;
    if (lane < 8)  ((int*)h2_lds)[lane] = 0;

    // ---- register-resident L1 weights: gates i, f ----
    int w1i[32], w1f[32];
    {
        const float* wri = w_hh1 + (size_t)lane * H1;
        const float* wrf = w_hh1 + (size_t)(H1 + lane) * H1;
        #pragma unroll
        for (int k = 0; k < 32; ++k) {
            w1i[k] = packh2(wri[2 * k], wri[2 * k + 1]);
            w1f[k] = packh2(wrf[2 * k], wrf[2 * k + 1]);
        }
    }
    // ---- LDS-streamed weights: g rows 0..7, o rows 8..15, w2 rows 16..23,
    //      wh2 rows 24..25 (hoisted to regs below). Lane-private columns. ----
    const int m  = lane >> 2;
    const int g2 = lane & 3;
    const int r2 = g2 * H2 + m;
    {
        const float* wrg = w_hh1 + (size_t)(2 * H1 + lane) * H1;
        const float* wro = w_hh1 + (size_t)(3 * H1 + lane) * H1;
        const float* wr2 = w_ih2 + (size_t)r2 * H1;
        #pragma unroll
        for (int tq = 0; tq < 8; ++tq) {
            wlds[tq][lane] = make_int4(
                packh2(wrg[8*tq+0], wrg[8*tq+1]), packh2(wrg[8*tq+2], wrg[8*tq+3]),
                packh2(wrg[8*tq+4], wrg[8*tq+5]), packh2(wrg[8*tq+6], wrg[8*tq+7]));
            wlds[8 + tq][lane] = make_int4(
                packh2(wro[8*tq+0], wro[8*tq+1]), packh2(wro[8*tq+2], wro[8*tq+3]),
                packh2(wro[8*tq+4], wro[8*tq+5]), packh2(wro[8*tq+6], wro[8*tq+7]));
            wlds[16 + tq][lane] = make_int4(
                packh2(wr2[8*tq+0], wr2[8*tq+1]), packh2(wr2[8*tq+2], wr2[8*tq+3]),
                packh2(wr2[8*tq+4], wr2[8*tq+5]), packh2(wr2[8*tq+6], wr2[8*tq+7]));
        }
        const float* wrh = w_hh2 + (size_t)r2 * H2;
        wlds[24][lane] = make_int4(packh2(wrh[0], wrh[1]),  packh2(wrh[2], wrh[3]),
                                   packh2(wrh[4], wrh[5]),  packh2(wrh[6], wrh[7]));
        wlds[25][lane] = make_int4(packh2(wrh[8], wrh[9]),  packh2(wrh[10], wrh[11]),
                                   packh2(wrh[12], wrh[13]), packh2(wrh[14], wrh[15]));
    }

    // ---- per-gate scalars ----
    const float wxi = w_ih1[lane],        wxf = w_ih1[H1 + lane];
    const float wxg = w_ih1[2*H1 + lane], wxo = w_ih1[3*H1 + lane];
    const float bsi = b_ih1[lane] + b_hh1[lane];
    const float bsf = b_ih1[H1+lane] + b_hh1[H1+lane];
    const float bsg = b_ih1[2*H1+lane] + b_hh1[2*H1+lane];
    const float bso = b_ih1[3*H1+lane] + b_hh1[3*H1+lane];
    const float bs2 = b_ih2[r2] + b_hh2[r2];
    const float k22 = (g2 == 2) ? 2.0f : 1.0f;

    float c1 = 0.0f;
    float c2 = 0.0f;
    float* outb = out + (size_t)b * TSTEPS * H2;

    const int4* wl  = &wlds[0][0];       // index row*64 + lane
    const int4* hs4 = (const int4*)h1_lds;

    // hoisted wh2 (8 regs) and ping-pong chunk buffers
    int4 vh0r = wl[24 * 64 + lane];
    int4 vh1r = wl[25 * 64 + lane];
    int4 wbA[6], wbB[6];
    #pragma unroll
    for (int j = 0; j < 2; ++j) {        // preload chunk 0 -> wbA
        wbA[0 + 3*j] = wl[(0 + j)  * 64 + lane];   // cg, cg2
        wbA[1 + 3*j] = wl[(8 + j)  * 64 + lane];   // co, co2  (order fixed below)
    }
    // (explicit, readable preload)
    wbA[0] = wl[(0)  * 64 + lane];  wbA[1] = wl[(1)  * 64 + lane];
    wbA[2] = wl[(8)  * 64 + lane];  wbA[3] = wl[(9)  * 64 + lane];
    wbA[4] = wl[(16) * 64 + lane];  wbA[5] = wl[(17) * 64 + lane];

    int4 hA = make_int4(0,0,0,0), hB = make_int4(0,0,0,0);   // h1(-1) pair0 = 0

// issue chunk Q's 6 streamed reads into buffer WB
#define ISSUE(WB, Q) do {                                        \
    WB[0] = wl[(2*(Q))      * 64 + lane];                        \
    WB[1] = wl[(2*(Q) + 1)  * 64 + lane];                        \
    WB[2] = wl[(8 + 2*(Q))  * 64 + lane];                        \
    WB[3] = wl[(9 + 2*(Q))  * 64 + lane];                        \
    WB[4] = wl[(16 + 2*(Q)) * 64 + lane];                        \
    WB[5] = wl[(17 + 2*(Q)) * 64 + lane];                        \
} while (0)

// dots for one chunk C using buffer WU and h pair (hA,hB)
#define DOTS(C, WU) do {                                                     \
    ai = dot2(w1i[8*C+0], hA.x, ai); ai = dot2(w1i[8*C+1], hA.y, ai);        \
    ai = dot2(w1i[8*C+2], hA.z, ai); ai = dot2(w1i[8*C+3], hA.w, ai);        \
    ai = dot2(w1i[8*C+4], hB.x, ai); ai = dot2(w1i[8*C+5], hB.y, ai);        \
    ai = dot2(w1i[8*C+6], hB.z, ai); ai = dot2(w1i[8*C+7], hB.w, ai);        \
    af = dot2(w1f[8*C+0], hA.x, af); af = dot2(w1f[8*C+1], hA.y, af);        \
    af = dot2(w1f[8*C+2], hA.z, af); af = dot2(w1f[8*C+3], hA.w, af);        \
    af = dot2(w1f[8*C+4], hB.x, af); af = dot2(w1f[8*C+5], hB.y, af);        \
    af = dot2(w1f[8*C+6], hB.z, af); af = dot2(w1f[8*C+7], hB.w, af);        \
    ag = dot2(WU[0].x, hA.x, ag); ag = dot2(WU[0].y, hA.y, ag);              \
    ag = dot2(WU[0].z, hA.z, ag); ag = dot2(WU[0].w, hA.w, ag);              \
    ag = dot2(WU[1].x, hB.x, ag); ag = dot2(WU[1].y, hB.y, ag);              \
    ag = dot2(WU[1].z, hB.z, ag); ag = dot2(WU[1].w, hB.w, ag);              \
    ao = dot2(WU[2].x, hA.x, ao); ao = dot2(WU[2].y, hA.y, ao);              \
    ao = dot2(WU[2].z, hA.z, ao); ao = dot2(WU[2].w, hA.w, ao);              \
    ao = dot2(WU[3].x, hB.x, ao); ao = dot2(WU[3].y, hB.y, ao);              \
    ao = dot2(WU[3].z, hB.z, ao); ao = dot2(WU[3].w, hB.w, ao);              \
    a0  = dot2(WU[4].x, hA.x, a0);  a1  = dot2(WU[4].y, hA.y, a1);           \
    a2a = dot2(WU[4].z, hA.z, a2a); a3  = dot2(WU[4].w, hA.w, a3);           \
    a0  = dot2(WU[5].x, hB.x, a0);  a1  = dot2(WU[5].y, hB.y, a1);           \
    a2a = dot2(WU[5].z, hB.z, a2a); a3  = dot2(WU[5].w, hB.w, a3);           \
} while (0)

    for (int p = 0; p <= TSTEPS; ++p) {
        // ---- pre-read h2(p-2) early (used in L2 finish, ~200 cyc later) ----
        const int4* h2p = (const int4*)h2_lds;
        int4 u0 = h2p[0], u1 = h2p[1];

        // ---- output flush: every 16 steps, slots written 16-31 steps ago ----
        const int tau_f = p - 1;
        if (tau_f >= 31 && (tau_f & 15) == 15) {
            const int tau0 = (tau_f & ~15) - 16;
            const int tt = tau0 + (lane >> 2), ch0 = (lane & 3) * 4;
            float4 v = *(const float4*)&ring[tt & 31][ch0];
            *(float4*)(outb + (size_t)tt * H2 + ch0) = v;      // 1 KB coalesced
        }

        // ---- gate accumulators ----
        const float xv = x_lds[p & (TSTEPS - 1)];
        float ai = bsi + wxi * xv;
        float af = bsf + wxf * xv;
        float ag = bsg + wxg * xv;
        float ao = bso + wxo * xv;
        float a0 = bs2, a1 = 0.f, a2a = 0.f, a3 = 0.f;

        // ---- 4 phases: issue chunk c+1's loads, then dots on chunk c ----
        {
            int4 nA, nB;
            // phase 0: uses wbA(ch0), issues ch1 -> wbB
            ISSUE(wbB, 1);
            nA = hs4[2]; nB = hs4[3];
            DOTS(0, wbA);
            hA = nA; hB = nB;
            // phase 1: uses wbB(ch1), issues ch2 -> wbA
            ISSUE(wbA, 2);
            nA = hs4[4]; nB = hs4[5];
            DOTS(1, wbB);
            hA = nA; hB = nB;
            // phase 2: uses wbA(ch2), issues ch3 -> wbB
            ISSUE(wbB, 3);
            nA = hs4[6]; nB = hs4[7];
            DOTS(2, wbA);
            hA = nA; hB = nB;
            // phase 3: uses wbB(ch3), issues NEXT STEP ch0 -> wbA
            ISSUE(wbA, 0);
            DOTS(3, wbB);
        }

        // ===== Layer 1 finish, timestep p =====
        if (p < TSTEPS) {
            float gi = fsig(ai), gf = fsig(af), gg = ftanh(ag), go = fsig(ao);
            c1 = gf * c1 + gi * gg;
            float h1n = go * ftanh(c1);
            h1_lds[lane] = (_Float16)h1n;       // ds_write_b16; same-wave FIFO
        }
        // prefetch next step's h pair0 NOW (after the write; DS FIFO makes it
        // see the new values; latency hides under the L2 finish below)
        hA = hs4[0]; hB = hs4[1];

        // ===== Layer 2 finish, timestep p-1 (same wave, no sync) =====
        if (p >= 1) {
            a0  = dot2(vh0r.x, u0.x, a0);  a1  = dot2(vh0r.y, u0.y, a1);
            a2a = dot2(vh0r.z, u0.z, a2a); a3  = dot2(vh0r.w, u0.w, a3);
            a0  = dot2(vh1r.x, u1.x, a0);  a1  = dot2(vh1r.y, u1.y, a1);
            a2a = dot2(vh1r.z, u1.z, a2a); a3  = dot2(vh1r.w, u1.w, a3);
            float av = act((a0 + a1) + (a2a + a3), k22);
            float gi = dpp_bcast<0x00>(av);     // quad holds (i,f,g,o) of channel m
            float gf = dpp_bcast<0x55>(av);
            float gg = dpp_bcast<0xAA>(av);
            float go = dpp_bcast<0xFF>(av);
            c2 = gf * c2 + gi * gg;
            float h2n = go * ftanh(c2);
            if (g2 == 0) {
                h2_lds[m] = (_Float16)h2n;
                ring[(p - 1) & 31][m] = h2n;
            }
        }
    }
#undef DOTS
#undef ISSUE

    // ---- tail flush: timesteps 2032..2047 (same wave -> FIFO safe) ----
    {
        const int tt = 2032 + (lane >> 2), ch0 = (lane & 3) * 4;
        float4 v = *(const float4*)&ring[tt & 31][ch0];
        *(float4*)(outb + (size_t)tt * H2 + ch0) = v;
    }
}

extern "C" void kernel_launch(void* const* d_in, const int* in_sizes, int n_in,
                              void* d_out, int out_size, void* d_ws, size_t ws_size,
                              hipStream_t stream) {
    const float* x     = (const float*)d_in[0];
    const float* w_ih1 = (const float*)d_in[1];
    const float* w_hh1 = (const float*)d_in[2];
    const float* b_ih1 = (const float*)d_in[3];
    const float* b_hh1 = (const float*)d_in[4];
    const float* w_ih2 = (const float*)d_in[5];
    const float* w_hh2 = (const float*)d_in[6];
    const float* b_ih2 = (const float*)d_in[7];
    const float* b_hh2 = (const float*)d_in[8];
    float* out = (float*)d_out;

    lstm2_fused<<<NBATCH, 64, 0, stream>>>(x, w_ih1, w_hh1, b_ih1, b_hh1,
                                           w_ih2, w_hh2, b_ih2, b_hh2, out);
}